// Round 16
// baseline (525.446 us; speedup 1.0000x reference)
//
#include <hip/hip_runtime.h>
#include <hip/hip_bf16.h>

#define N_NODES 20000
#define N_EDGES 320000
#define N_E2    (N_EDGES + N_NODES)   // 340000 edges incl self loops
#define N_GRAPHS 256
#define HID 256
#define EPS 1e-5f
#define NSCAN 20                       // ceil(20000/1024)
#define CPB 2                          // 64-edge chunks per k_alpha3 block (measured optimum)

typedef unsigned short u16;
typedef __attribute__((ext_vector_type(8))) short short8;
typedef __attribute__((ext_vector_type(4))) float f32x4;

__device__ __forceinline__ float b2f(u16 u) {
    union { unsigned int i; float f; } v; v.i = ((unsigned int)u) << 16; return v.f;
}
__device__ __forceinline__ u16 f2b(float f) {
    __hip_bfloat16 h = __float2bfloat16(f);   // RNE
    return *reinterpret_cast<u16*>(&h);
}

// ---------------------------------------------------------------- CSR build
__global__ void k_count(const int* __restrict__ dst, int* __restrict__ cnt) {
    int e = blockIdx.x * 256 + threadIdx.x;
    if (e < N_EDGES) atomicAdd(&cnt[dst[e]], 1);
}

// scan over (cnt[i] + 1): the +1 is the self loop (cnt/cursor zeroed by memset)
__global__ void k_scan1(const int* __restrict__ cnt, int* __restrict__ rowp, int* __restrict__ part) {
    __shared__ int ls[256];
    int b = blockIdx.x, tid = threadIdx.x;
    int base = b * 1024 + tid * 4;
    int c[4]; int s = 0;
#pragma unroll
    for (int u = 0; u < 4; u++) { int i = base + u; c[u] = (i < N_NODES) ? cnt[i] + 1 : 0; s += c[u]; }
    ls[tid] = s; __syncthreads();
    for (int off = 1; off < 256; off <<= 1) {
        int v = (tid >= off) ? ls[tid - off] : 0;
        __syncthreads();
        ls[tid] += v;
        __syncthreads();
    }
    int excl = ls[tid] - s;
#pragma unroll
    for (int u = 0; u < 4; u++) { int i = base + u; if (i < N_NODES) rowp[i] = excl; excl += c[u]; }
    if (tid == 255) part[b] = ls[255];
}

__global__ void k_scan2(int* part, int* rowp) {
    int s = 0;
    for (int b = 0; b < NSCAN; b++) { int v = part[b]; part[b] = s; s += v; }
    rowp[N_NODES] = s;   // == N_E2
}

__global__ void k_scan3(int* __restrict__ rowp, const int* __restrict__ part) {
    int b = blockIdx.x, tid = threadIdx.x;
    int add = part[b];
    int base = b * 1024 + tid * 4;
#pragma unroll
    for (int u = 0; u < 4; u++) { int i = base + u; if (i < N_NODES) rowp[i] += add; }
}

// fill CSR; tail threads zero the +512 padding
__global__ void k_fill(const int* __restrict__ src, const int* __restrict__ dst,
                       const int* __restrict__ rowp, int* __restrict__ cursor,
                       int* __restrict__ csr_src, int* __restrict__ csr_dst,
                       int* __restrict__ csr_aid) {
    int t = blockIdx.x * 256 + threadIdx.x;
    if (t < N_EDGES) {
        int d = dst[t];
        int pos = atomicAdd(&cursor[d], 1);
        int w = rowp[d] + pos;
        csr_src[w] = src[t];
        csr_dst[w] = d;
        csr_aid[w] = t;
    } else if (t < N_E2) {
        int n = t - N_EDGES;
        int pos = atomicAdd(&cursor[n], 1);
        int w = rowp[n] + pos;
        csr_src[w] = n;
        csr_dst[w] = n;
        csr_aid[w] = N_EDGES + n;   // self loop, attr = mean of incoming
    } else if (t < N_E2 + 512) {
        csr_src[t] = 0;
        csr_dst[t] = 0;
    }
}

// ea_bf[e][0:16] = bf16(edge_attr[csr_aid[e]]); self-loop rows computed inline
// as the mean of the node's incoming edge_attr.
__global__ void k_eacsr(const int* __restrict__ csr_aid, const int* __restrict__ rowp,
                        const float* __restrict__ edge_attr,
                        u16* __restrict__ ea_bf) {
    int t = blockIdx.x * 256 + threadIdx.x;   // one thread per 8 attrs
    if (t >= N_E2 * 2) return;
    int e = t >> 1, hf = t & 1;
    int aid = csr_aid[e];
    float v[8];
    if (aid < N_EDGES) {
        const float4* ap = (const float4*)(edge_attr + (size_t)aid * 16 + hf * 8);
        float4 a = ap[0], b = ap[1];
        v[0] = a.x; v[1] = a.y; v[2] = a.z; v[3] = a.w;
        v[4] = b.x; v[5] = b.y; v[6] = b.z; v[7] = b.w;
    } else {
        int n = aid - N_EDGES;
        int st = rowp[n], en = rowp[n + 1];
        float s[8] = {0.f, 0.f, 0.f, 0.f, 0.f, 0.f, 0.f, 0.f};
        for (int i = st; i < en; i++) {
            int a2 = csr_aid[i];
            if (a2 < N_EDGES) {
                const float4* ap = (const float4*)(edge_attr + (size_t)a2 * 16 + hf * 8);
                float4 a = ap[0], b = ap[1];
                s[0] += a.x; s[1] += a.y; s[2] += a.z; s[3] += a.w;
                s[4] += b.x; s[5] += b.y; s[6] += b.z; s[7] += b.w;
            }
        }
        float rdeg = 1.0f / fmaxf((float)(en - st - 1), 1.0f);
#pragma unroll
        for (int q = 0; q < 8; q++) v[q] = s[q] * rdeg;
    }
    u16 o[8];
#pragma unroll
    for (int q = 0; q < 8; q++) o[q] = f2b(v[q]);
    *(uint4*)(ea_bf + (size_t)t * 8) = *(uint4*)o;
}

// We[layer][16][256] fp32 -> fragment layout Wef[layer][nt][lane][8] bf16 (K padded to 32)
__global__ void k_wef(const float* __restrict__ We, u16* __restrict__ Wef) {
    int t = blockIdx.x * 256 + threadIdx.x;   // 3*16*64 = 3072
    if (t >= 3 * 16 * 64) return;
    int layer = t >> 10, r = t & 1023;
    int nt = r >> 6, l = r & 63;
    int kc = l >> 4, ch = nt * 16 + (l & 15);
    u16 v[8];
#pragma unroll
    for (int q = 0; q < 8; q++) {
        float x = 0.f;
        if (kc < 2) x = We[(size_t)layer * 4096 + (size_t)(kc * 8 + q) * 256 + ch];
        v[q] = f2b(x);
    }
    *(uint4*)(Wef + (size_t)t * 8) = *(uint4*)v;
}

// x (fp32) -> bf16
__global__ void k_xbf(const float* __restrict__ x, u16* __restrict__ xb) {
    int t = blockIdx.x * 256 + threadIdx.x;   // N*64/4 threads
    if (t >= N_NODES * 16) return;
    float4 v = ((const float4*)x)[t];
    u16 o[4] = {f2b(v.x), f2b(v.y), f2b(v.z), f2b(v.w)};
    *(ushort4*)(xb + (size_t)t * 4) = *(ushort4*)o;
}

// W[layer][K][N] fp32 -> Wt[layer(lstride)][N][K] bf16 (32x32 LDS tile transpose)
__global__ void k_twg(const float* __restrict__ W, u16* __restrict__ Wt, int K, int N,
                      unsigned int lstride) {
    __shared__ float tile[32][33];
    int layer = blockIdx.z;
    const float* Wp = W + (size_t)layer * K * N;
    u16* Wtp = Wt + (size_t)layer * lstride;
    int bk = blockIdx.x * 32, bn = blockIdx.y * 32;
    int tx = threadIdx.x & 31, ty = threadIdx.x >> 5; // 32 x 8
#pragma unroll
    for (int q = 0; q < 4; q++) {
        int k = bk + ty + q * 8;
        tile[ty + q * 8][tx] = Wp[(size_t)k * N + bn + tx];
    }
    __syncthreads();
#pragma unroll
    for (int q = 0; q < 4; q++) {
        int n = bn + ty + q * 8;
        Wtp[(size_t)n * K + bk + tx] = f2b(tile[tx][ty + q * 8]);
    }
}

// concat conv_bl / conv_br -> blr[layer][512]
__global__ void k_blr(const float* __restrict__ bl, const float* __restrict__ br,
                      float* __restrict__ blr) {
    int t = blockIdx.x * 256 + threadIdx.x;   // 3*512
    if (t >= 3 * 512) return;
    int l = t >> 9, c = t & 511;
    blr[t] = (c < 256) ? bl[l * 256 + c] : br[l * 256 + (c - 256)];
}

// ---------------------------------------------------------------- GEMM bf16 MFMA
template <int EPI>
__global__ __launch_bounds__(256) void k_gemm_bf(
    const u16* __restrict__ A, int lda,
    const u16* __restrict__ Bt, int ldb, int K,
    const float* __restrict__ bias,
    u16* __restrict__ Cbf, int ldc, int coff,
    float* __restrict__ Cf, int M)
{
    __shared__ __align__(16) u16 As[128 * 40];   // [128][32+8]
    __shared__ __align__(16) u16 Bs[64 * 40];    // [64][32+8]
    int tid = threadIdx.x;
    int lane = tid & 63, w = tid >> 6;
    int m0 = blockIdx.x * 128, n0 = blockIdx.y * 64;

    f32x4 acc[2][4];
#pragma unroll
    for (int i = 0; i < 2; i++)
#pragma unroll
        for (int j = 0; j < 4; j++) acc[i][j] = (f32x4){0.f, 0.f, 0.f, 0.f};

    int srow = tid >> 2, skc = (tid & 3) * 8;    // staging: row, k-chunk
    int lr = lane & 15, lk = (lane >> 4) * 8;

    int ktiles = K >> 5;
    for (int kt = 0; kt < ktiles; kt++) {
        if (kt) __syncthreads();
#pragma unroll
        for (int q = 0; q < 2; q++) {
            int arow = q * 64 + srow;
            uint4 av = make_uint4(0, 0, 0, 0);
            if (m0 + arow < M)
                av = *(const uint4*)(A + (size_t)(m0 + arow) * lda + kt * 32 + skc);
            *(uint4*)&As[arow * 40 + skc] = av;
        }
        {
            uint4 bv = *(const uint4*)(Bt + (size_t)(n0 + srow) * ldb + kt * 32 + skc);
            *(uint4*)&Bs[srow * 40 + skc] = bv;
        }
        __syncthreads();

        short8 af0 = *(const short8*)&As[(w * 32 + lr) * 40 + lk];
        short8 af1 = *(const short8*)&As[(w * 32 + 16 + lr) * 40 + lk];
        short8 bf[4];
#pragma unroll
        for (int nt = 0; nt < 4; nt++)
            bf[nt] = *(const short8*)&Bs[(nt * 16 + lr) * 40 + lk];
#pragma unroll
        for (int nt = 0; nt < 4; nt++) {
            acc[0][nt] = __builtin_amdgcn_mfma_f32_16x16x32_bf16(af0, bf[nt], acc[0][nt], 0, 0, 0);
            acc[1][nt] = __builtin_amdgcn_mfma_f32_16x16x32_bf16(af1, bf[nt], acc[1][nt], 0, 0, 0);
        }
    }

    // C/D layout: col = lane&15, row = (lane>>4)*4 + j
    int rq = (lane >> 4) * 4;
#pragma unroll
    for (int nt = 0; nt < 4; nt++) {
        int col = n0 + nt * 16 + lr;
        float bv = bias[col];
#pragma unroll
        for (int mt = 0; mt < 2; mt++) {
#pragma unroll
            for (int j = 0; j < 4; j++) {
                int row = m0 + w * 32 + mt * 16 + rq + j;
                if (row < M) {
                    float v = acc[mt][nt][j] + bv;
                    if (EPI == 1) {
                        v = fmaxf(v, 0.f);
                        Cf[(size_t)row * ldc + col] = v;
                        Cbf[(size_t)row * ldc + col] = f2b(v);
                    } else {
                        Cbf[(size_t)row * ldc + coff + col] = f2b(v);
                    }
                }
            }
        }
    }
}

// ---------------------------------------------------------------- GATv2 pass 1: alpha per edge
// R7's layout: D = ea · Wef_nt -> row = edge (eg*4+j), col = ch (t16).
// Writes ex = exp(alpha) (no max shift: |alpha| << 88) and accumulates
// den[node][head] via fp32 atomics, so k_aggr needs no softmax reductions.
__global__ __launch_bounds__(256) void k_alpha3(
    const u16* __restrict__ xlr,        // [N,512] bf16 xl|xr
    const u16* __restrict__ ea_bf,      // [E2,16] bf16 CSR order
    const int* __restrict__ csr_src, const int* __restrict__ csr_dst,  // padded +512
    const u16* __restrict__ Wef,        // [16][64][8] bf16 fragments, this layer
    const float* __restrict__ att,      // [256]
    float* __restrict__ exw,            // [E2,4] = exp(alpha)
    float* __restrict__ den)            // [N,4] zero-initialized
{
    __shared__ __align__(16) u16 wef_s[16 * 64 * 8];   // 16 KB
    int tid = threadIdx.x, lane = tid & 63, w = tid >> 6;
    {
        const uint4* s = (const uint4*)Wef;
        uint4* d = (uint4*)wef_s;
#pragma unroll
        for (int q = 0; q < 4; q++) d[q * 256 + tid] = s[q * 256 + tid];
    }
    int eg = lane >> 4, t16 = lane & 15;

    float att_r[16];
#pragma unroll
    for (int q = 0; q < 16; q++) att_r[q] = att[q * 16 + t16];
    __syncthreads();

    for (int it = 0; it < CPB; it++) {
        int chunk = blockIdx.x * CPB + it;
        if (chunk * 64 >= N_E2) break;
        int e_base = chunk * 64 + w * 16;

        // A fragment: row = t16 (edge), k-chunk = eg (0,1 real; 2,3 zero-pad)
        short8 afrag = {0, 0, 0, 0, 0, 0, 0, 0};
        if (eg < 2) {
            int e = e_base + t16; if (e > N_E2 - 1) e = N_E2 - 1;
            afrag = *(const short8*)(ea_bf + (size_t)e * 16 + eg * 8);
        }
        int4 s4 = *(const int4*)(csr_src + e_base + eg * 4);
        int4 d4 = *(const int4*)(csr_dst + e_base + eg * 4);
        int darr[4] = {d4.x, d4.y, d4.z, d4.w};
        const u16* xlp[4]; const u16* xrp[4];
        xlp[0] = xlr + (size_t)s4.x * 512;       xlp[1] = xlr + (size_t)s4.y * 512;
        xlp[2] = xlr + (size_t)s4.z * 512;       xlp[3] = xlr + (size_t)s4.w * 512;
        xrp[0] = xlr + (size_t)d4.x * 512 + 256; xrp[1] = xlr + (size_t)d4.y * 512 + 256;
        xrp[2] = xlr + (size_t)d4.z * 512 + 256; xrp[3] = xlr + (size_t)d4.w * 512 + 256;

        float pj[4] = {0.f, 0.f, 0.f, 0.f};
#pragma unroll
        for (int nt = 0; nt < 16; nt++) {
            short8 bfrag = *(const short8*)&wef_s[(nt * 64 + lane) * 8];
            f32x4 D = __builtin_amdgcn_mfma_f32_16x16x32_bf16(
                afrag, bfrag, (f32x4){0.f, 0.f, 0.f, 0.f}, 0, 0, 0);
            int ch = nt * 16 + t16;
#pragma unroll
            for (int j = 0; j < 4; j++) {
                float z = D[j] + b2f(xlp[j][ch]) + b2f(xrp[j][ch]);
                z = fmaxf(z, 0.f) + 0.2f * fminf(z, 0.f);   // leaky_relu 0.2
                pj[j] = fmaf(z, att_r[nt], pj[j]);
            }
            if ((nt & 3) == 3) {
                int hh = nt >> 2;
#pragma unroll
                for (int j = 0; j < 4; j++) {
                    float p = pj[j];
                    p += __shfl_xor(p, 1, 64);
                    p += __shfl_xor(p, 2, 64);
                    p += __shfl_xor(p, 4, 64);
                    p += __shfl_xor(p, 8, 64);
                    int e = e_base + eg * 4 + j;
                    if (t16 == 0 && e < N_E2) {
                        float ex = __expf(p);
                        exw[(size_t)e * 4 + hh] = ex;
                        atomicAdd(&den[(size_t)darr[j] * 4 + hh], ex);
                    }
                    pj[j] = 0.f;
                }
            }
        }
    }
}

// ---------------------------------------------------------------- GATv2 pass 2: weighted aggregate
// exw holds exp(alpha); den holds per-(node,head) sums. No reductions needed.
__global__ __launch_bounds__(256) void k_aggr(
    const u16* __restrict__ xlr, const float* __restrict__ exw,
    const float* __restrict__ den,
    const int* __restrict__ rowp, const int* __restrict__ csr_src,
    const float* __restrict__ cbias,
    const float* __restrict__ bng, const float* __restrict__ bnb,
    const float* __restrict__ bnm, const float* __restrict__ bnv,
    float* __restrict__ h, u16* __restrict__ h_bf)   // [N,256] in/out + bf16 copy
{
    __shared__ float lex[4][64][4];      // [wave][edge-in-chunk][head]
    __shared__ int   lsrc[4][64];
    int lane = threadIdx.x & 63;
    int wv = threadIdx.x >> 6;
    int n = blockIdx.x * 4 + wv;
    if (n >= N_NODES) return;
    int st = rowp[n], en = rowp[n + 1];
    int hsel = lane >> 4;                // head owning channels c0..c0+3
    int c0 = lane * 4;

    float acc[4] = {0.f, 0.f, 0.f, 0.f};

    for (int cs = st; cs < en; cs += 64) {
        int cnt = min(64, en - cs);
        float4 v = make_float4(0.f, 0.f, 0.f, 0.f);
        int s_i = 0;
        if (lane < cnt) {
            v = *(const float4*)(exw + (size_t)(cs + lane) * 4);
            s_i = csr_src[cs + lane];
        }
        *(float4*)&lex[wv][lane][0] = v;
        lsrc[wv][lane] = s_i;
        // weighted gather-sum: 8 row-gathers (8B bf16x4) in flight per step
        int j = 0;
        for (; j + 8 <= cnt; j += 8) {
            float a[8]; int sj[8];
#pragma unroll
            for (int q = 0; q < 8; q++) { a[q] = lex[wv][j + q][hsel]; sj[q] = lsrc[wv][j + q]; }
            ushort4 xg[8];
#pragma unroll
            for (int q = 0; q < 8; q++) xg[q] = *(const ushort4*)(xlr + (size_t)sj[q] * 512 + c0);
#pragma unroll
            for (int q = 0; q < 8; q++) {
                acc[0] += a[q] * b2f(((const u16*)&xg[q])[0]);
                acc[1] += a[q] * b2f(((const u16*)&xg[q])[1]);
                acc[2] += a[q] * b2f(((const u16*)&xg[q])[2]);
                acc[3] += a[q] * b2f(((const u16*)&xg[q])[3]);
            }
        }
        for (; j < cnt; j++) {
            float a = lex[wv][j][hsel];
            int sj = lsrc[wv][j];
            ushort4 xg = *(const ushort4*)(xlr + (size_t)sj * 512 + c0);
            acc[0] += a * b2f(((const u16*)&xg)[0]);
            acc[1] += a * b2f(((const u16*)&xg)[1]);
            acc[2] += a * b2f(((const u16*)&xg)[2]);
            acc[3] += a * b2f(((const u16*)&xg)[3]);
        }
    }

    float dd = den[(size_t)n * 4 + hsel];
    float4 hin = *(const float4*)(h + (size_t)n * 256 + c0);
    float4 cb  = *(const float4*)(cbias + c0);
    float4 gg  = *(const float4*)(bng + c0);
    float4 bb  = *(const float4*)(bnb + c0);
    float4 mm  = *(const float4*)(bnm + c0);
    float4 vv  = *(const float4*)(bnv + c0);
    float hi[4] = {hin.x, hin.y, hin.z, hin.w};
    float cbv[4] = {cb.x, cb.y, cb.z, cb.w};
    float gv[4] = {gg.x, gg.y, gg.z, gg.w};
    float bv[4] = {bb.x, bb.y, bb.z, bb.w};
    float mv[4] = {mm.x, mm.y, mm.z, mm.w};
    float vvv[4] = {vv.x, vv.y, vv.z, vv.w};
    float4 o;
    ushort4 ob;
#pragma unroll
    for (int u = 0; u < 4; u++) {
        float val = acc[u] / dd + cbv[u];
        val = (val - mv[u]) * rsqrtf(vvv[u] + EPS) * gv[u] + bv[u];
        val = fmaxf(val, 0.f) + hi[u];
        ((float*)&o)[u] = val;
        ((u16*)&ob)[u] = f2b(val);
    }
    *(float4*)(h + (size_t)n * 256 + c0) = o;
    *(ushort4*)(h_bf + (size_t)n * 256 + c0) = ob;
}

// ---------------------------------------------------------------- pooling partials (parallel)
__global__ __launch_bounds__(256) void k_poolp(
    const float* __restrict__ h, float* __restrict__ psum, float* __restrict__ pmax)
{
    int g = blockIdx.x, p = blockIdx.y, c = threadIdx.x;
    int gst = (g * N_NODES + N_GRAPHS - 1) / N_GRAPHS;
    int gen = ((g + 1) * N_NODES + N_GRAPHS - 1) / N_GRAPHS;
    int len = gen - gst;
    int cst = gst + (len * p) / 8;
    int cen = gst + (len * (p + 1)) / 8;
    float s = 0.f, mx = -3.0e38f;
    for (int i = cst; i < cen; i++) {
        float v = h[(size_t)i * 256 + c];
        s += v;
        mx = fmaxf(mx, v);
    }
    psum[(size_t)(g * 8 + p) * 256 + c] = s;
    pmax[(size_t)(g * 8 + p) * 256 + c] = mx;
}

// ---------------------------------------------------------------- fused classifier head
__global__ __launch_bounds__(256) void k_head(
    const float* __restrict__ psum, const float* __restrict__ pmax,
    const float* __restrict__ W1, const float* __restrict__ b1,
    const float* __restrict__ g1, const float* __restrict__ bt1,
    const float* __restrict__ m1, const float* __restrict__ v1,
    const float* __restrict__ W2, const float* __restrict__ b2,
    const float* __restrict__ g2, const float* __restrict__ bt2,
    const float* __restrict__ m2, const float* __restrict__ v2,
    const float* __restrict__ W3, const float* __restrict__ b3,
    float* __restrict__ out)
{
    __shared__ float xp_s[512];
    __shared__ float z1_s[256];
    __shared__ float z2p[2][128];
    __shared__ float z2_s[128];
    int g = blockIdx.x, c = threadIdx.x;
    int gst = (g * N_NODES + N_GRAPHS - 1) / N_GRAPHS;
    int gen = ((g + 1) * N_NODES + N_GRAPHS - 1) / N_GRAPHS;

    float s = 0.f, mx = -3.0e38f;
#pragma unroll
    for (int p = 0; p < 8; p++) {
        s += psum[(size_t)(g * 8 + p) * 256 + c];
        mx = fmaxf(mx, pmax[(size_t)(g * 8 + p) * 256 + c]);
    }
    xp_s[c] = s / (float)(gen - gst);
    xp_s[256 + c] = mx;
    __syncthreads();

    float a0 = 0.f, a1 = 0.f, a2 = 0.f, a3 = 0.f;
#pragma unroll 4
    for (int k = 0; k < 512; k += 4) {
        a0 = fmaf(xp_s[k + 0], W1[(k + 0) * 256 + c], a0);
        a1 = fmaf(xp_s[k + 1], W1[(k + 1) * 256 + c], a1);
        a2 = fmaf(xp_s[k + 2], W1[(k + 2) * 256 + c], a2);
        a3 = fmaf(xp_s[k + 3], W1[(k + 3) * 256 + c], a3);
    }
    float a = (a0 + a1) + (a2 + a3) + b1[c];
    a = (a - m1[c]) * rsqrtf(v1[c] + EPS) * g1[c] + bt1[c];
    z1_s[c] = fmaxf(a, 0.f);
    __syncthreads();

    {
        int c2 = c & 127, half = c >> 7;
        float b_acc = 0.f;
#pragma unroll 4
        for (int k = 0; k < 128; k++) {
            int kk = half * 128 + k;
            b_acc = fmaf(z1_s[kk], W2[kk * 128 + c2], b_acc);
        }
        z2p[half][c2] = b_acc;
    }
    __syncthreads();
    if (c < 128) {
        float a2v = z2p[0][c] + z2p[1][c] + b2[c];
        a2v = (a2v - m2[c]) * rsqrtf(v2[c] + EPS) * g2[c] + bt2[c];
        z2_s[c] = fmaxf(a2v, 0.f);
    }
    __syncthreads();

    if (c < 64) {
        float a3v = z2_s[c] * W3[c] + z2_s[c + 64] * W3[c + 64];
#pragma unroll
        for (int o = 32; o >= 1; o >>= 1) a3v += __shfl_xor(a3v, o, 64);
        if (c == 0) out[g] = a3v + b3[0];
    }
}

// ---------------------------------------------------------------- launch
extern "C" void kernel_launch(void* const* d_in, const int* in_sizes, int n_in,
                              void* d_out, int out_size, void* d_ws, size_t ws_size,
                              hipStream_t stream) {
    const float* x         = (const float*)d_in[0];
    const int*   ei        = (const int*)d_in[1];
    const int*   src       = ei;
    const int*   dst       = ei + N_EDGES;
    const float* edge_attr = (const float*)d_in[3];
    const float* enc_W     = (const float*)d_in[4];
    const float* enc_b     = (const float*)d_in[5];
    const float* conv_Wl   = (const float*)d_in[6];
    const float* conv_bl   = (const float*)d_in[7];
    const float* conv_Wr   = (const float*)d_in[8];
    const float* conv_br   = (const float*)d_in[9];
    const float* conv_We   = (const float*)d_in[10];
    const float* conv_att  = (const float*)d_in[11];
    const float* conv_bias = (const float*)d_in[12];
    const float* bn_g      = (const float*)d_in[13];
    const float* bn_b      = (const float*)d_in[14];
    const float* bn_m      = (const float*)d_in[15];
    const float* bn_v      = (const float*)d_in[16];
    const float* cls_W1    = (const float*)d_in[17];
    const float* cls_b1    = (const float*)d_in[18];
    const float* cls_g1    = (const float*)d_in[19];
    const float* cls_bt1   = (const float*)d_in[20];
    const float* cls_m1    = (const float*)d_in[21];
    const float* cls_v1    = (const float*)d_in[22];
    const float* cls_W2    = (const float*)d_in[23];
    const float* cls_b2    = (const float*)d_in[24];
    const float* cls_g2    = (const float*)d_in[25];
    const float* cls_bt2   = (const float*)d_in[26];
    const float* cls_m2    = (const float*)d_in[27];
    const float* cls_v2    = (const float*)d_in[28];
    const float* cls_W3    = (const float*)d_in[29];
    const float* cls_b3    = (const float*)d_in[30];
    float* out = (float*)d_out;

    char* ws = (char*)d_ws;
    size_t off = 0;
    auto alloc = [&](size_t bytes) -> void* {
        void* p = ws + off;
        off += (bytes + 255) & ~(size_t)255;
        return p;
    };
    float* h       = (float*)alloc((size_t)N_NODES * 256 * 4);    // 20.5 MB
    u16*   h_bf    = (u16*)alloc((size_t)N_NODES * 256 * 2);      // 10.2 MB
    u16*   xlr_bf  = (u16*)alloc((size_t)N_NODES * 512 * 2);      // 20.5 MB
    u16*   ea_bf   = (u16*)alloc((size_t)N_E2 * 16 * 2);          // 10.9 MB
    float* exw     = (float*)alloc((size_t)N_E2 * 4 * 4);         // 5.4 MB
    u16*   x_bf    = (u16*)alloc((size_t)N_NODES * 64 * 2);       // 2.6 MB
    u16*   enc_Wt  = (u16*)alloc((size_t)64 * 256 * 2);           // 32 KB
    u16*   Wtlr    = (u16*)alloc((size_t)3 * 512 * 256 * 2);      // 786 KB
    float* blr     = (float*)alloc((size_t)3 * 512 * 4);          // 6 KB
    u16*   Wef     = (u16*)alloc((size_t)3 * 16 * 64 * 8 * 2);    // 48 KB
    float* psum    = (float*)alloc((size_t)N_GRAPHS * 8 * 256 * 4); // 2 MB
    float* pmax    = (float*)alloc((size_t)N_GRAPHS * 8 * 256 * 4); // 2 MB
    int*   cntcur  = (int*)alloc((size_t)2 * N_NODES * 4);        // cnt | cursor
    int*   cnt     = cntcur;
    int*   cursor  = cntcur + N_NODES;
    float* den3    = (float*)alloc((size_t)3 * N_NODES * 4 * 4);  // 0.96 MB, per-layer den
    int*   rowp    = (int*)alloc((size_t)(N_NODES + 1) * 4);
    int*   csr_src = (int*)alloc((size_t)(N_E2 + 512) * 4);
    int*   csr_dst = (int*)alloc((size_t)(N_E2 + 512) * 4);
    int*   csr_aid = (int*)alloc((size_t)N_E2 * 4);
    int*   part    = (int*)alloc(64 * 4);

    // zero cnt|cursor and all three per-layer den buffers (contiguous allocs)
    hipMemsetAsync(cntcur, 0, (size_t)2 * N_NODES * 4, stream);
    hipMemsetAsync(den3, 0, (size_t)3 * N_NODES * 4 * 4, stream);

    // CSR build
    k_count<<<(N_EDGES + 255) / 256, 256, 0, stream>>>(dst, cnt);
    k_scan1<<<NSCAN, 256, 0, stream>>>(cnt, rowp, part);
    k_scan2<<<1, 1, 0, stream>>>(part, rowp);
    k_scan3<<<NSCAN, 256, 0, stream>>>(rowp, part);
    k_fill<<<(N_E2 + 512 + 255) / 256, 256, 0, stream>>>(src, dst, rowp, cursor,
                                                         csr_src, csr_dst, csr_aid);
    k_eacsr<<<(N_E2 * 2 + 255) / 256, 256, 0, stream>>>(csr_aid, rowp, edge_attr, ea_bf);

    // weight / input prep
    k_xbf<<<(N_NODES * 16 + 255) / 256, 256, 0, stream>>>(x, x_bf);
    k_twg<<<dim3(2, 8, 1), 256, 0, stream>>>(enc_W, enc_Wt, 64, 256, 64 * 256);
    k_twg<<<dim3(8, 8, 3), 256, 0, stream>>>(conv_Wl, Wtlr, 256, 256, 512 * 256);
    k_twg<<<dim3(8, 8, 3), 256, 0, stream>>>(conv_Wr, Wtlr + 256 * 256, 256, 256, 512 * 256);
    k_blr<<<6, 256, 0, stream>>>(conv_bl, conv_br, blr);
    k_wef<<<12, 256, 0, stream>>>(conv_We, Wef);

    dim3 ggrid((N_NODES + 127) / 128, 4);
    dim3 ggrid2((N_NODES + 127) / 128, 8);
    // encoder: h = relu(x @ enc_W + enc_b) via MFMA, emits h fp32 + h_bf
    k_gemm_bf<1><<<ggrid, 256, 0, stream>>>(x_bf, 64, enc_Wt, 64, 64,
                                            enc_b, h_bf, 256, 0, h, N_NODES);

    // 3 GATv2 layers: merged Wl|Wr GEMM + alpha(exp+den) + weighted aggregate
    int nchunks = (N_E2 + 63) / 64;               // 5313
    int ablocks = (nchunks + CPB - 1) / CPB;      // 2657
    for (int i = 0; i < 3; i++) {
        float* den = den3 + (size_t)i * N_NODES * 4;
        k_gemm_bf<0><<<ggrid2, 256, 0, stream>>>(h_bf, 256, Wtlr + (size_t)i * 131072, 256, 256,
                                                 blr + (size_t)i * 512, xlr_bf, 512, 0, nullptr, N_NODES);
        k_alpha3<<<ablocks, 256, 0, stream>>>(
            xlr_bf, ea_bf, csr_src, csr_dst,
            Wef + (size_t)i * 8192, conv_att + (size_t)i * 256, exw, den);
        k_aggr<<<N_NODES / 4, 256, 0, stream>>>(
            xlr_bf, exw, den, rowp, csr_src,
            conv_bias + (size_t)i * HID,
            bn_g + (size_t)i * HID, bn_b + (size_t)i * HID,
            bn_m + (size_t)i * HID, bn_v + (size_t)i * HID, h, h_bf);
    }

    // pooling partials + fused classifier
    k_poolp<<<dim3(N_GRAPHS, 8), 256, 0, stream>>>(h, psum, pmax);
    k_head<<<N_GRAPHS, 256, 0, stream>>>(
        psum, pmax, cls_W1, cls_b1, cls_g1, cls_bt1, cls_m1, cls_v1,
        cls_W2, cls_b2, cls_g2, cls_bt2, cls_m2, cls_v2,
        cls_W3, cls_b3, out);
}

// Round 17
// 432.550 us; speedup vs baseline: 1.2148x; 1.2148x over previous
//
#include <hip/hip_runtime.h>
#include <hip/hip_bf16.h>

#define N_NODES 20000
#define N_EDGES 320000
#define N_E2    (N_EDGES + N_NODES)   // 340000 edges incl self loops
#define N_GRAPHS 256
#define HID 256
#define EPS 1e-5f
#define NSCAN 20                       // ceil(20000/1024)
#define CPB 2                          // 64-edge chunks per k_alpha3 block (measured optimum)

typedef unsigned short u16;
typedef __attribute__((ext_vector_type(8))) short short8;
typedef __attribute__((ext_vector_type(4))) float f32x4;

__device__ __forceinline__ float b2f(u16 u) {
    union { unsigned int i; float f; } v; v.i = ((unsigned int)u) << 16; return v.f;
}
__device__ __forceinline__ u16 f2b(float f) {
    __hip_bfloat16 h = __float2bfloat16(f);   // RNE
    return *reinterpret_cast<u16*>(&h);
}

// ---------------------------------------------------------------- CSR build
__global__ void k_count(const int* __restrict__ dst, int* __restrict__ cnt) {
    int e = blockIdx.x * 256 + threadIdx.x;
    if (e < N_EDGES) atomicAdd(&cnt[dst[e]], 1);
}

// scan over (cnt[i] + 1): the +1 is the self loop (cnt/cursor zeroed by memset)
__global__ void k_scan1(const int* __restrict__ cnt, int* __restrict__ rowp, int* __restrict__ part) {
    __shared__ int ls[256];
    int b = blockIdx.x, tid = threadIdx.x;
    int base = b * 1024 + tid * 4;
    int c[4]; int s = 0;
#pragma unroll
    for (int u = 0; u < 4; u++) { int i = base + u; c[u] = (i < N_NODES) ? cnt[i] + 1 : 0; s += c[u]; }
    ls[tid] = s; __syncthreads();
    for (int off = 1; off < 256; off <<= 1) {
        int v = (tid >= off) ? ls[tid - off] : 0;
        __syncthreads();
        ls[tid] += v;
        __syncthreads();
    }
    int excl = ls[tid] - s;
#pragma unroll
    for (int u = 0; u < 4; u++) { int i = base + u; if (i < N_NODES) rowp[i] = excl; excl += c[u]; }
    if (tid == 255) part[b] = ls[255];
}

__global__ void k_scan2(int* part, int* rowp) {
    int s = 0;
    for (int b = 0; b < NSCAN; b++) { int v = part[b]; part[b] = s; s += v; }
    rowp[N_NODES] = s;   // == N_E2
}

__global__ void k_scan3(int* __restrict__ rowp, const int* __restrict__ part) {
    int b = blockIdx.x, tid = threadIdx.x;
    int add = part[b];
    int base = b * 1024 + tid * 4;
#pragma unroll
    for (int u = 0; u < 4; u++) { int i = base + u; if (i < N_NODES) rowp[i] += add; }
}

// fill CSR; tail threads zero the +512 padding
__global__ void k_fill(const int* __restrict__ src, const int* __restrict__ dst,
                       const int* __restrict__ rowp, int* __restrict__ cursor,
                       int* __restrict__ csr_src, int* __restrict__ csr_dst,
                       int* __restrict__ csr_aid) {
    int t = blockIdx.x * 256 + threadIdx.x;
    if (t < N_EDGES) {
        int d = dst[t];
        int pos = atomicAdd(&cursor[d], 1);
        int w = rowp[d] + pos;
        csr_src[w] = src[t];
        csr_dst[w] = d;
        csr_aid[w] = t;
    } else if (t < N_E2) {
        int n = t - N_EDGES;
        int pos = atomicAdd(&cursor[n], 1);
        int w = rowp[n] + pos;
        csr_src[w] = n;
        csr_dst[w] = n;
        csr_aid[w] = N_EDGES + n;   // self loop, attr = mean of incoming
    } else if (t < N_E2 + 512) {
        csr_src[t] = 0;
        csr_dst[t] = 0;
    }
}

// ea_bf[e][0:16] = bf16(edge_attr[csr_aid[e]]); self-loop rows computed inline
// as the mean of the node's incoming edge_attr.
__global__ void k_eacsr(const int* __restrict__ csr_aid, const int* __restrict__ rowp,
                        const float* __restrict__ edge_attr,
                        u16* __restrict__ ea_bf) {
    int t = blockIdx.x * 256 + threadIdx.x;   // one thread per 8 attrs
    if (t >= N_E2 * 2) return;
    int e = t >> 1, hf = t & 1;
    int aid = csr_aid[e];
    float v[8];
    if (aid < N_EDGES) {
        const float4* ap = (const float4*)(edge_attr + (size_t)aid * 16 + hf * 8);
        float4 a = ap[0], b = ap[1];
        v[0] = a.x; v[1] = a.y; v[2] = a.z; v[3] = a.w;
        v[4] = b.x; v[5] = b.y; v[6] = b.z; v[7] = b.w;
    } else {
        int n = aid - N_EDGES;
        int st = rowp[n], en = rowp[n + 1];
        float s[8] = {0.f, 0.f, 0.f, 0.f, 0.f, 0.f, 0.f, 0.f};
        for (int i = st; i < en; i++) {
            int a2 = csr_aid[i];
            if (a2 < N_EDGES) {
                const float4* ap = (const float4*)(edge_attr + (size_t)a2 * 16 + hf * 8);
                float4 a = ap[0], b = ap[1];
                s[0] += a.x; s[1] += a.y; s[2] += a.z; s[3] += a.w;
                s[4] += b.x; s[5] += b.y; s[6] += b.z; s[7] += b.w;
            }
        }
        float rdeg = 1.0f / fmaxf((float)(en - st - 1), 1.0f);
#pragma unroll
        for (int q = 0; q < 8; q++) v[q] = s[q] * rdeg;
    }
    u16 o[8];
#pragma unroll
    for (int q = 0; q < 8; q++) o[q] = f2b(v[q]);
    *(uint4*)(ea_bf + (size_t)t * 8) = *(uint4*)o;
}

// We[layer][16][256] fp32 -> fragment layout Wef[layer][nt][lane][8] bf16 (K padded to 32)
__global__ void k_wef(const float* __restrict__ We, u16* __restrict__ Wef) {
    int t = blockIdx.x * 256 + threadIdx.x;   // 3*16*64 = 3072
    if (t >= 3 * 16 * 64) return;
    int layer = t >> 10, r = t & 1023;
    int nt = r >> 6, l = r & 63;
    int kc = l >> 4, ch = nt * 16 + (l & 15);
    u16 v[8];
#pragma unroll
    for (int q = 0; q < 8; q++) {
        float x = 0.f;
        if (kc < 2) x = We[(size_t)layer * 4096 + (size_t)(kc * 8 + q) * 256 + ch];
        v[q] = f2b(x);
    }
    *(uint4*)(Wef + (size_t)t * 8) = *(uint4*)v;
}

// x (fp32) -> bf16
__global__ void k_xbf(const float* __restrict__ x, u16* __restrict__ xb) {
    int t = blockIdx.x * 256 + threadIdx.x;   // N*64/4 threads
    if (t >= N_NODES * 16) return;
    float4 v = ((const float4*)x)[t];
    u16 o[4] = {f2b(v.x), f2b(v.y), f2b(v.z), f2b(v.w)};
    *(ushort4*)(xb + (size_t)t * 4) = *(ushort4*)o;
}

// W[layer][K][N] fp32 -> Wt[layer(lstride)][N][K] bf16 (32x32 LDS tile transpose)
__global__ void k_twg(const float* __restrict__ W, u16* __restrict__ Wt, int K, int N,
                      unsigned int lstride) {
    __shared__ float tile[32][33];
    int layer = blockIdx.z;
    const float* Wp = W + (size_t)layer * K * N;
    u16* Wtp = Wt + (size_t)layer * lstride;
    int bk = blockIdx.x * 32, bn = blockIdx.y * 32;
    int tx = threadIdx.x & 31, ty = threadIdx.x >> 5; // 32 x 8
#pragma unroll
    for (int q = 0; q < 4; q++) {
        int k = bk + ty + q * 8;
        tile[ty + q * 8][tx] = Wp[(size_t)k * N + bn + tx];
    }
    __syncthreads();
#pragma unroll
    for (int q = 0; q < 4; q++) {
        int n = bn + ty + q * 8;
        Wtp[(size_t)n * K + bk + tx] = f2b(tile[tx][ty + q * 8]);
    }
}

// concat conv_bl / conv_br -> blr[layer][512]
__global__ void k_blr(const float* __restrict__ bl, const float* __restrict__ br,
                      float* __restrict__ blr) {
    int t = blockIdx.x * 256 + threadIdx.x;   // 3*512
    if (t >= 3 * 512) return;
    int l = t >> 9, c = t & 511;
    blr[t] = (c < 256) ? bl[l * 256 + c] : br[l * 256 + (c - 256)];
}

// ---------------------------------------------------------------- GEMM bf16 MFMA
template <int EPI>
__global__ __launch_bounds__(256) void k_gemm_bf(
    const u16* __restrict__ A, int lda,
    const u16* __restrict__ Bt, int ldb, int K,
    const float* __restrict__ bias,
    u16* __restrict__ Cbf, int ldc, int coff,
    float* __restrict__ Cf, int M)
{
    __shared__ __align__(16) u16 As[128 * 40];   // [128][32+8]
    __shared__ __align__(16) u16 Bs[64 * 40];    // [64][32+8]
    int tid = threadIdx.x;
    int lane = tid & 63, w = tid >> 6;
    int m0 = blockIdx.x * 128, n0 = blockIdx.y * 64;

    f32x4 acc[2][4];
#pragma unroll
    for (int i = 0; i < 2; i++)
#pragma unroll
        for (int j = 0; j < 4; j++) acc[i][j] = (f32x4){0.f, 0.f, 0.f, 0.f};

    int srow = tid >> 2, skc = (tid & 3) * 8;    // staging: row, k-chunk
    int lr = lane & 15, lk = (lane >> 4) * 8;

    int ktiles = K >> 5;
    for (int kt = 0; kt < ktiles; kt++) {
        if (kt) __syncthreads();
#pragma unroll
        for (int q = 0; q < 2; q++) {
            int arow = q * 64 + srow;
            uint4 av = make_uint4(0, 0, 0, 0);
            if (m0 + arow < M)
                av = *(const uint4*)(A + (size_t)(m0 + arow) * lda + kt * 32 + skc);
            *(uint4*)&As[arow * 40 + skc] = av;
        }
        {
            uint4 bv = *(const uint4*)(Bt + (size_t)(n0 + srow) * ldb + kt * 32 + skc);
            *(uint4*)&Bs[srow * 40 + skc] = bv;
        }
        __syncthreads();

        short8 af0 = *(const short8*)&As[(w * 32 + lr) * 40 + lk];
        short8 af1 = *(const short8*)&As[(w * 32 + 16 + lr) * 40 + lk];
        short8 bf[4];
#pragma unroll
        for (int nt = 0; nt < 4; nt++)
            bf[nt] = *(const short8*)&Bs[(nt * 16 + lr) * 40 + lk];
#pragma unroll
        for (int nt = 0; nt < 4; nt++) {
            acc[0][nt] = __builtin_amdgcn_mfma_f32_16x16x32_bf16(af0, bf[nt], acc[0][nt], 0, 0, 0);
            acc[1][nt] = __builtin_amdgcn_mfma_f32_16x16x32_bf16(af1, bf[nt], acc[1][nt], 0, 0, 0);
        }
    }

    // C/D layout: col = lane&15, row = (lane>>4)*4 + j
    int rq = (lane >> 4) * 4;
#pragma unroll
    for (int nt = 0; nt < 4; nt++) {
        int col = n0 + nt * 16 + lr;
        float bv = bias[col];
#pragma unroll
        for (int mt = 0; mt < 2; mt++) {
#pragma unroll
            for (int j = 0; j < 4; j++) {
                int row = m0 + w * 32 + mt * 16 + rq + j;
                if (row < M) {
                    float v = acc[mt][nt][j] + bv;
                    if (EPI == 1) {
                        v = fmaxf(v, 0.f);
                        Cf[(size_t)row * ldc + col] = v;
                        Cbf[(size_t)row * ldc + col] = f2b(v);
                    } else {
                        Cbf[(size_t)row * ldc + coff + col] = f2b(v);
                    }
                }
            }
        }
    }
}

// ---------------------------------------------------------------- GATv2 pass 1: alpha per edge
// R7's verified-fastest layout: D = ea · Wef_nt -> row = edge (eg*4+j), col = ch (t16).
// one wave per 16 edges, CPB chunks per block (Wef staged once per block).
__global__ __launch_bounds__(256) void k_alpha3(
    const u16* __restrict__ xlr,        // [N,512] bf16 xl|xr
    const u16* __restrict__ ea_bf,      // [E2,16] bf16 CSR order
    const int* __restrict__ csr_src, const int* __restrict__ csr_dst,  // padded +512
    const u16* __restrict__ Wef,        // [16][64][8] bf16 fragments, this layer
    const float* __restrict__ att,      // [256]
    float* __restrict__ alpha)          // [E2,4]
{
    __shared__ __align__(16) u16 wef_s[16 * 64 * 8];   // 16 KB
    int tid = threadIdx.x, lane = tid & 63, w = tid >> 6;
    {
        const uint4* s = (const uint4*)Wef;
        uint4* d = (uint4*)wef_s;
#pragma unroll
        for (int q = 0; q < 4; q++) d[q * 256 + tid] = s[q * 256 + tid];
    }
    int eg = lane >> 4, t16 = lane & 15;

    float att_r[16];
#pragma unroll
    for (int q = 0; q < 16; q++) att_r[q] = att[q * 16 + t16];
    __syncthreads();

    for (int it = 0; it < CPB; it++) {
        int chunk = blockIdx.x * CPB + it;
        if (chunk * 64 >= N_E2) break;
        int e_base = chunk * 64 + w * 16;

        // A fragment: row = t16 (edge), k-chunk = eg (0,1 real; 2,3 zero-pad)
        short8 afrag = {0, 0, 0, 0, 0, 0, 0, 0};
        if (eg < 2) {
            int e = e_base + t16; if (e > N_E2 - 1) e = N_E2 - 1;
            afrag = *(const short8*)(ea_bf + (size_t)e * 16 + eg * 8);
        }
        int4 s4 = *(const int4*)(csr_src + e_base + eg * 4);
        int4 d4 = *(const int4*)(csr_dst + e_base + eg * 4);
        const u16* xlp[4]; const u16* xrp[4];
        xlp[0] = xlr + (size_t)s4.x * 512;       xlp[1] = xlr + (size_t)s4.y * 512;
        xlp[2] = xlr + (size_t)s4.z * 512;       xlp[3] = xlr + (size_t)s4.w * 512;
        xrp[0] = xlr + (size_t)d4.x * 512 + 256; xrp[1] = xlr + (size_t)d4.y * 512 + 256;
        xrp[2] = xlr + (size_t)d4.z * 512 + 256; xrp[3] = xlr + (size_t)d4.w * 512 + 256;

        float pj[4] = {0.f, 0.f, 0.f, 0.f};
#pragma unroll
        for (int nt = 0; nt < 16; nt++) {
            short8 bfrag = *(const short8*)&wef_s[(nt * 64 + lane) * 8];
            f32x4 D = __builtin_amdgcn_mfma_f32_16x16x32_bf16(
                afrag, bfrag, (f32x4){0.f, 0.f, 0.f, 0.f}, 0, 0, 0);
            int ch = nt * 16 + t16;
#pragma unroll
            for (int j = 0; j < 4; j++) {
                float z = D[j] + b2f(xlp[j][ch]) + b2f(xrp[j][ch]);
                z = fmaxf(z, 0.f) + 0.2f * fminf(z, 0.f);   // leaky_relu 0.2
                pj[j] = fmaf(z, att_r[nt], pj[j]);
            }
            if ((nt & 3) == 3) {
                int hh = nt >> 2;
#pragma unroll
                for (int j = 0; j < 4; j++) {
                    float p = pj[j];
                    p += __shfl_xor(p, 1, 64);
                    p += __shfl_xor(p, 2, 64);
                    p += __shfl_xor(p, 4, 64);
                    p += __shfl_xor(p, 8, 64);
                    int e = e_base + eg * 4 + j;
                    if (t16 == 0 && e < N_E2) alpha[(size_t)e * 4 + hh] = p;
                    pj[j] = 0.f;
                }
            }
        }
    }
}

// ---------------------------------------------------------------- GATv2 pass 2: softmax + aggregate
__global__ __launch_bounds__(256) void k_aggr(
    const u16* __restrict__ xlr, const float* __restrict__ alpha,
    const int* __restrict__ rowp, const int* __restrict__ csr_src,
    const float* __restrict__ cbias,
    const float* __restrict__ bng, const float* __restrict__ bnb,
    const float* __restrict__ bnm, const float* __restrict__ bnv,
    float* __restrict__ h, u16* __restrict__ h_bf)   // [N,256] in/out + bf16 copy
{
    __shared__ float lex[4][64][4];      // [wave][edge-in-chunk][head]
    __shared__ int   lsrc[4][64];
    int lane = threadIdx.x & 63;
    int wv = threadIdx.x >> 6;
    int n = blockIdx.x * 4 + wv;
    if (n >= N_NODES) return;
    int st = rowp[n], en = rowp[n + 1];
    int hsel = lane >> 4;                // head owning channels c0..c0+3
    int c0 = lane * 4;

    float m4[4]  = {-3.0e38f, -3.0e38f, -3.0e38f, -3.0e38f};
    float den4[4] = {0.f, 0.f, 0.f, 0.f};
    float acc[4]  = {0.f, 0.f, 0.f, 0.f};

    for (int cs = st; cs < en; cs += 64) {
        int cnt = min(64, en - cs);
        float a4[4];
        int s_i = 0;
        if (lane < cnt) {
            float4 v = *(const float4*)(alpha + (size_t)(cs + lane) * 4);
            a4[0] = v.x; a4[1] = v.y; a4[2] = v.z; a4[3] = v.w;
            s_i = csr_src[cs + lane];
        } else {
            a4[0] = a4[1] = a4[2] = a4[3] = -3.0e38f;
        }
        float cm[4] = {a4[0], a4[1], a4[2], a4[3]};
#pragma unroll
        for (int o = 32; o >= 1; o >>= 1)
#pragma unroll
            for (int u = 0; u < 4; u++) cm[u] = fmaxf(cm[u], __shfl_xor(cm[u], o, 64));
        float sc[4];
#pragma unroll
        for (int u = 0; u < 4; u++) {
            float nm = fmaxf(m4[u], cm[u]);
            sc[u] = __expf(m4[u] - nm);
            den4[u] *= sc[u];
            m4[u] = nm;
        }
        float scl = sc[hsel];
#pragma unroll
        for (int u = 0; u < 4; u++) acc[u] *= scl;
        float ex[4];
#pragma unroll
        for (int u = 0; u < 4; u++) ex[u] = (lane < cnt) ? __expf(a4[u] - m4[u]) : 0.f;
        float sx[4] = {ex[0], ex[1], ex[2], ex[3]};
#pragma unroll
        for (int o = 32; o >= 1; o >>= 1)
#pragma unroll
            for (int u = 0; u < 4; u++) sx[u] += __shfl_xor(sx[u], o, 64);
#pragma unroll
        for (int u = 0; u < 4; u++) den4[u] += sx[u];
        *(float4*)&lex[wv][lane][0] = make_float4(ex[0], ex[1], ex[2], ex[3]);
        lsrc[wv][lane] = s_i;
        // weighted gather-sum: 8 row-gathers (8B bf16x4) in flight per step
        int j = 0;
        for (; j + 8 <= cnt; j += 8) {
            float a[8]; int sj[8];
#pragma unroll
            for (int q = 0; q < 8; q++) { a[q] = lex[wv][j + q][hsel]; sj[q] = lsrc[wv][j + q]; }
            ushort4 xg[8];
#pragma unroll
            for (int q = 0; q < 8; q++) xg[q] = *(const ushort4*)(xlr + (size_t)sj[q] * 512 + c0);
#pragma unroll
            for (int q = 0; q < 8; q++) {
                acc[0] += a[q] * b2f(((const u16*)&xg[q])[0]);
                acc[1] += a[q] * b2f(((const u16*)&xg[q])[1]);
                acc[2] += a[q] * b2f(((const u16*)&xg[q])[2]);
                acc[3] += a[q] * b2f(((const u16*)&xg[q])[3]);
            }
        }
        for (; j < cnt; j++) {
            float a = lex[wv][j][hsel];
            int sj = lsrc[wv][j];
            ushort4 xg = *(const ushort4*)(xlr + (size_t)sj * 512 + c0);
            acc[0] += a * b2f(((const u16*)&xg)[0]);
            acc[1] += a * b2f(((const u16*)&xg)[1]);
            acc[2] += a * b2f(((const u16*)&xg)[2]);
            acc[3] += a * b2f(((const u16*)&xg)[3]);
        }
    }

    float dd = den4[hsel];
    float4 hin = *(const float4*)(h + (size_t)n * 256 + c0);
    float4 cb  = *(const float4*)(cbias + c0);
    float4 gg  = *(const float4*)(bng + c0);
    float4 bb  = *(const float4*)(bnb + c0);
    float4 mm  = *(const float4*)(bnm + c0);
    float4 vv  = *(const float4*)(bnv + c0);
    float hi[4] = {hin.x, hin.y, hin.z, hin.w};
    float cbv[4] = {cb.x, cb.y, cb.z, cb.w};
    float gv[4] = {gg.x, gg.y, gg.z, gg.w};
    float bv[4] = {bb.x, bb.y, bb.z, bb.w};
    float mv[4] = {mm.x, mm.y, mm.z, mm.w};
    float vvv[4] = {vv.x, vv.y, vv.z, vv.w};
    float4 o;
    ushort4 ob;
#pragma unroll
    for (int u = 0; u < 4; u++) {
        float val = acc[u] / dd + cbv[u];
        val = (val - mv[u]) * rsqrtf(vvv[u] + EPS) * gv[u] + bv[u];
        val = fmaxf(val, 0.f) + hi[u];
        ((float*)&o)[u] = val;
        ((u16*)&ob)[u] = f2b(val);
    }
    *(float4*)(h + (size_t)n * 256 + c0) = o;
    *(ushort4*)(h_bf + (size_t)n * 256 + c0) = ob;
}

// ---------------------------------------------------------------- pooling partials (parallel)
__global__ __launch_bounds__(256) void k_poolp(
    const float* __restrict__ h, float* __restrict__ psum, float* __restrict__ pmax)
{
    int g = blockIdx.x, p = blockIdx.y, c = threadIdx.x;
    int gst = (g * N_NODES + N_GRAPHS - 1) / N_GRAPHS;
    int gen = ((g + 1) * N_NODES + N_GRAPHS - 1) / N_GRAPHS;
    int len = gen - gst;
    int cst = gst + (len * p) / 8;
    int cen = gst + (len * (p + 1)) / 8;
    float s = 0.f, mx = -3.0e38f;
    for (int i = cst; i < cen; i++) {
        float v = h[(size_t)i * 256 + c];
        s += v;
        mx = fmaxf(mx, v);
    }
    psum[(size_t)(g * 8 + p) * 256 + c] = s;
    pmax[(size_t)(g * 8 + p) * 256 + c] = mx;
}

// ---------------------------------------------------------------- fused classifier head
__global__ __launch_bounds__(256) void k_head(
    const float* __restrict__ psum, const float* __restrict__ pmax,
    const float* __restrict__ W1, const float* __restrict__ b1,
    const float* __restrict__ g1, const float* __restrict__ bt1,
    const float* __restrict__ m1, const float* __restrict__ v1,
    const float* __restrict__ W2, const float* __restrict__ b2,
    const float* __restrict__ g2, const float* __restrict__ bt2,
    const float* __restrict__ m2, const float* __restrict__ v2,
    const float* __restrict__ W3, const float* __restrict__ b3,
    float* __restrict__ out)
{
    __shared__ float xp_s[512];
    __shared__ float z1_s[256];
    __shared__ float z2p[2][128];
    __shared__ float z2_s[128];
    int g = blockIdx.x, c = threadIdx.x;
    int gst = (g * N_NODES + N_GRAPHS - 1) / N_GRAPHS;
    int gen = ((g + 1) * N_NODES + N_GRAPHS - 1) / N_GRAPHS;

    float s = 0.f, mx = -3.0e38f;
#pragma unroll
    for (int p = 0; p < 8; p++) {
        s += psum[(size_t)(g * 8 + p) * 256 + c];
        mx = fmaxf(mx, pmax[(size_t)(g * 8 + p) * 256 + c]);
    }
    xp_s[c] = s / (float)(gen - gst);
    xp_s[256 + c] = mx;
    __syncthreads();

    float a0 = 0.f, a1 = 0.f, a2 = 0.f, a3 = 0.f;
#pragma unroll 4
    for (int k = 0; k < 512; k += 4) {
        a0 = fmaf(xp_s[k + 0], W1[(k + 0) * 256 + c], a0);
        a1 = fmaf(xp_s[k + 1], W1[(k + 1) * 256 + c], a1);
        a2 = fmaf(xp_s[k + 2], W1[(k + 2) * 256 + c], a2);
        a3 = fmaf(xp_s[k + 3], W1[(k + 3) * 256 + c], a3);
    }
    float a = (a0 + a1) + (a2 + a3) + b1[c];
    a = (a - m1[c]) * rsqrtf(v1[c] + EPS) * g1[c] + bt1[c];
    z1_s[c] = fmaxf(a, 0.f);
    __syncthreads();

    {
        int c2 = c & 127, half = c >> 7;
        float b_acc = 0.f;
#pragma unroll 4
        for (int k = 0; k < 128; k++) {
            int kk = half * 128 + k;
            b_acc = fmaf(z1_s[kk], W2[kk * 128 + c2], b_acc);
        }
        z2p[half][c2] = b_acc;
    }
    __syncthreads();
    if (c < 128) {
        float a2v = z2p[0][c] + z2p[1][c] + b2[c];
        a2v = (a2v - m2[c]) * rsqrtf(v2[c] + EPS) * g2[c] + bt2[c];
        z2_s[c] = fmaxf(a2v, 0.f);
    }
    __syncthreads();

    if (c < 64) {
        float a3v = z2_s[c] * W3[c] + z2_s[c + 64] * W3[c + 64];
#pragma unroll
        for (int o = 32; o >= 1; o >>= 1) a3v += __shfl_xor(a3v, o, 64);
        if (c == 0) out[g] = a3v + b3[0];
    }
}

// ---------------------------------------------------------------- launch
extern "C" void kernel_launch(void* const* d_in, const int* in_sizes, int n_in,
                              void* d_out, int out_size, void* d_ws, size_t ws_size,
                              hipStream_t stream) {
    const float* x         = (const float*)d_in[0];
    const int*   ei        = (const int*)d_in[1];
    const int*   src       = ei;
    const int*   dst       = ei + N_EDGES;
    const float* edge_attr = (const float*)d_in[3];
    const float* enc_W     = (const float*)d_in[4];
    const float* enc_b     = (const float*)d_in[5];
    const float* conv_Wl   = (const float*)d_in[6];
    const float* conv_bl   = (const float*)d_in[7];
    const float* conv_Wr   = (const float*)d_in[8];
    const float* conv_br   = (const float*)d_in[9];
    const float* conv_We   = (const float*)d_in[10];
    const float* conv_att  = (const float*)d_in[11];
    const float* conv_bias = (const float*)d_in[12];
    const float* bn_g      = (const float*)d_in[13];
    const float* bn_b      = (const float*)d_in[14];
    const float* bn_m      = (const float*)d_in[15];
    const float* bn_v      = (const float*)d_in[16];
    const float* cls_W1    = (const float*)d_in[17];
    const float* cls_b1    = (const float*)d_in[18];
    const float* cls_g1    = (const float*)d_in[19];
    const float* cls_bt1   = (const float*)d_in[20];
    const float* cls_m1    = (const float*)d_in[21];
    const float* cls_v1    = (const float*)d_in[22];
    const float* cls_W2    = (const float*)d_in[23];
    const float* cls_b2    = (const float*)d_in[24];
    const float* cls_g2    = (const float*)d_in[25];
    const float* cls_bt2   = (const float*)d_in[26];
    const float* cls_m2    = (const float*)d_in[27];
    const float* cls_v2    = (const float*)d_in[28];
    const float* cls_W3    = (const float*)d_in[29];
    const float* cls_b3    = (const float*)d_in[30];
    float* out = (float*)d_out;

    char* ws = (char*)d_ws;
    size_t off = 0;
    auto alloc = [&](size_t bytes) -> void* {
        void* p = ws + off;
        off += (bytes + 255) & ~(size_t)255;
        return p;
    };
    float* h       = (float*)alloc((size_t)N_NODES * 256 * 4);    // 20.5 MB
    u16*   h_bf    = (u16*)alloc((size_t)N_NODES * 256 * 2);      // 10.2 MB
    u16*   xlr_bf  = (u16*)alloc((size_t)N_NODES * 512 * 2);      // 20.5 MB
    u16*   ea_bf   = (u16*)alloc((size_t)N_E2 * 16 * 2);          // 10.9 MB
    float* alphas  = (float*)alloc((size_t)N_E2 * 4 * 4);         // 5.4 MB
    u16*   x_bf    = (u16*)alloc((size_t)N_NODES * 64 * 2);       // 2.6 MB
    u16*   enc_Wt  = (u16*)alloc((size_t)64 * 256 * 2);           // 32 KB
    u16*   Wtlr    = (u16*)alloc((size_t)3 * 512 * 256 * 2);      // 786 KB
    float* blr     = (float*)alloc((size_t)3 * 512 * 4);          // 6 KB
    u16*   Wef     = (u16*)alloc((size_t)3 * 16 * 64 * 8 * 2);    // 48 KB
    float* psum    = (float*)alloc((size_t)N_GRAPHS * 8 * 256 * 4); // 2 MB
    float* pmax    = (float*)alloc((size_t)N_GRAPHS * 8 * 256 * 4); // 2 MB
    int*   cntcur  = (int*)alloc((size_t)2 * N_NODES * 4);        // cnt | cursor (contiguous)
    int*   cnt     = cntcur;
    int*   cursor  = cntcur + N_NODES;
    int*   rowp    = (int*)alloc((size_t)(N_NODES + 1) * 4);
    int*   csr_src = (int*)alloc((size_t)(N_E2 + 512) * 4);
    int*   csr_dst = (int*)alloc((size_t)(N_E2 + 512) * 4);
    int*   csr_aid = (int*)alloc((size_t)N_E2 * 4);
    int*   part    = (int*)alloc(64 * 4);

    // CSR build (cnt+cursor zeroed in one memset; +1 self-loop folded into scan)
    hipMemsetAsync(cntcur, 0, (size_t)2 * N_NODES * 4, stream);
    k_count<<<(N_EDGES + 255) / 256, 256, 0, stream>>>(dst, cnt);
    k_scan1<<<NSCAN, 256, 0, stream>>>(cnt, rowp, part);
    k_scan2<<<1, 1, 0, stream>>>(part, rowp);
    k_scan3<<<NSCAN, 256, 0, stream>>>(rowp, part);
    k_fill<<<(N_E2 + 512 + 255) / 256, 256, 0, stream>>>(src, dst, rowp, cursor,
                                                         csr_src, csr_dst, csr_aid);
    k_eacsr<<<(N_E2 * 2 + 255) / 256, 256, 0, stream>>>(csr_aid, rowp, edge_attr, ea_bf);

    // weight / input prep
    k_xbf<<<(N_NODES * 16 + 255) / 256, 256, 0, stream>>>(x, x_bf);
    k_twg<<<dim3(2, 8, 1), 256, 0, stream>>>(enc_W, enc_Wt, 64, 256, 64 * 256);
    k_twg<<<dim3(8, 8, 3), 256, 0, stream>>>(conv_Wl, Wtlr, 256, 256, 512 * 256);
    k_twg<<<dim3(8, 8, 3), 256, 0, stream>>>(conv_Wr, Wtlr + 256 * 256, 256, 256, 512 * 256);
    k_blr<<<6, 256, 0, stream>>>(conv_bl, conv_br, blr);
    k_wef<<<12, 256, 0, stream>>>(conv_We, Wef);

    dim3 ggrid((N_NODES + 127) / 128, 4);
    dim3 ggrid2((N_NODES + 127) / 128, 8);
    // encoder: h = relu(x @ enc_W + enc_b) via MFMA, emits h fp32 + h_bf
    k_gemm_bf<1><<<ggrid, 256, 0, stream>>>(x_bf, 64, enc_Wt, 64, 64,
                                            enc_b, h_bf, 256, 0, h, N_NODES);

    // 3 GATv2 layers: merged Wl|Wr GEMM + alpha + aggregate
    int nchunks = (N_E2 + 63) / 64;               // 5313
    int ablocks = (nchunks + CPB - 1) / CPB;      // 2657
    for (int i = 0; i < 3; i++) {
        k_gemm_bf<0><<<ggrid2, 256, 0, stream>>>(h_bf, 256, Wtlr + (size_t)i * 131072, 256, 256,
                                                 blr + (size_t)i * 512, xlr_bf, 512, 0, nullptr, N_NODES);
        k_alpha3<<<ablocks, 256, 0, stream>>>(
            xlr_bf, ea_bf, csr_src, csr_dst,
            Wef + (size_t)i * 8192, conv_att + (size_t)i * 256, alphas);
        k_aggr<<<N_NODES / 4, 256, 0, stream>>>(
            xlr_bf, alphas, rowp, csr_src,
            conv_bias + (size_t)i * HID,
            bn_g + (size_t)i * HID, bn_b + (size_t)i * HID,
            bn_m + (size_t)i * HID, bn_v + (size_t)i * HID, h, h_bf);
    }

    // pooling partials + fused classifier
    k_poolp<<<dim3(N_GRAPHS, 8), 256, 0, stream>>>(h, psum, pmax);
    k_head<<<N_GRAPHS, 256, 0, stream>>>(
        psum, pmax, cls_W1, cls_b1, cls_g1, cls_bt1, cls_m1, cls_v1,
        cls_W2, cls_b2, cls_g2, cls_bt2, cls_m2, cls_v2,
        cls_W3, cls_b3, out);
}